// Round 8
// baseline (16.985 us; speedup 1.0000x reference)
//
#include <hip/hip_runtime.h>
#include <math.h>

#define DD 15          // feature dim
#define DP 20          // padded LDS row stride (80B, float4-aligned)
#define LL 64          // leaves
#define NCC 10         // num classes
#define TL 127         // full tree rows (leaves materialized at 63..126)
#define EPB 4          // batch elements per block (1 per wave)

// ---- DPP cross-lane (VALU pipe, no LDS) ----
__device__ __forceinline__ float dpp_xor1(float x) {   // quad_perm [1,0,3,2]
    return __int_as_float(__builtin_amdgcn_update_dpp(0, __float_as_int(x), 0xB1, 0xF, 0xF, true));
}
__device__ __forceinline__ float dpp_xor2(float x) {   // quad_perm [2,3,0,1]
    return __int_as_float(__builtin_amdgcn_update_dpp(0, __float_as_int(x), 0x4E, 0xF, 0xF, true));
}
__device__ __forceinline__ float dpp_hmirror(float x) { // row_half_mirror: u -> u^7 within 8
    return __int_as_float(__builtin_amdgcn_update_dpp(0, __float_as_int(x), 0x141, 0xF, 0xF, true));
}

// combine at one parent: 8 lanes cooperate.
// k = t&1 (W matrix), qr = (t>>1)&3 (4 A-rows), u = t&7 (2 output dims)
__device__ __forceinline__ void combine_ptr(const float* Lrow, const float* Rrow,
                                            const float w[4][DD], int k, int qr, int u,
                                            float& o0, float& o1)
{
    float4 R0 = ((const float4*)Rrow)[0];
    float4 R1 = ((const float4*)Rrow)[1];
    float4 R2 = ((const float4*)Rrow)[2];
    float4 R3 = ((const float4*)Rrow)[3];          // .w = pad col15 = 0
    float4 Aq = ((const float4*)Lrow)[qr];         // A dims 4qr..4qr+3 (row15 pad = 0)
    float2 lm = ((const float2*)Lrow)[u];          // dims 2u,2u+1
    float2 rm = ((const float2*)Rrow)[u];
    float Bv[DD] = {R0.x,R0.y,R0.z,R0.w, R1.x,R1.y,R1.z,R1.w,
                    R2.x,R2.y,R2.z,R2.w, R3.x,R3.y,R3.z};
    float Av[4] = {Aq.x, Aq.y, Aq.z, Aq.w};

    float p = 0.f;
    #pragma unroll
    for (int ri = 0; ri < 4; ++ri) {
        float dA = 0.f, dB = 0.f;                  // split chain: depth 8 not 15
        #pragma unroll
        for (int j = 0; j < 8; ++j)  dA = fmaf(w[ri][j], Bv[j], dA);
        #pragma unroll
        for (int j = 8; j < DD; ++j) dB = fmaf(w[ri][j], Bv[j], dB);
        p = fmaf(Av[ri], dA + dB, p);              // invalid row 15: w==0, Av==0
    }
    // reduce partials over qr bits (1,2), fetch partner-k logit — all DPP
    float a    = p + dpp_xor2(p);
    float hma  = dpp_hmirror(a);
    float self = a + dpp_xor1(hma);
    float oth  = dpp_xor1(a) + hma;
    // softmax of 2 == sigmoid(self - oth)
    float aS = __builtin_amdgcn_rcpf(1.0f + __expf(oth - self));
    float aO = 1.0f - aS;
    float a0 = (k == 0) ? aS : aO;                 // alpha for W0 (left child)
    float a1 = (k == 0) ? aO : aS;

    float v0 = fmaf(a0, lm.x, a1 * rm.x);
    float v1 = fmaf(a0, lm.y, a1 * rm.y);          // u==7: dim15 = 0
    float ss = v0 * v0 + v1 * v1;
    ss += dpp_xor1(ss);
    ss += dpp_xor2(ss);
    ss += dpp_hmirror(ss);
    float inv = __builtin_amdgcn_rsqf(ss * (1.0f / DD) + 1e-6f);
    o0 = v0 * inv; o1 = v1 * inv;
}

extern "C" __global__ __attribute__((amdgpu_flat_work_group_size(256, 256)))
void seg_tree_kernel(
    const float* __restrict__ emb,
    const float* __restrict__ W_lin,
    const float* __restrict__ W_rule,
    const int*  __restrict__ x,
    const int*  __restrict__ qlo_g,
    const int*  __restrict__ qhi_g,
    float* __restrict__ out,
    int bsz)
{
    __shared__ __align__(16) float nemb[NCC + 1][DP];
    __shared__ __align__(16) float tree[EPB][TL][DP];

    const int tb = threadIdx.x;
    const int wv = tb >> 6;
    const int t  = tb & 63;
    int b = blockIdx.x * EPB + wv;
    const bool active = (b < bsz);
    if (!active) b = bsz - 1;                 // clamp: redundant work, store guarded

    const int k = t & 1, qr = (t >> 1) & 3, u = t & 7, g = t >> 3;
    const int g2 = (t >> 3) & 1;              // 0 -> ql path, 1 -> qh path
    float (*tw)[DP] = tree[wv];

    // wave-uniform query bounds in SGPRs
    const int ql = __builtin_amdgcn_readfirstlane(qlo_g[b]);
    const int qh = __builtin_amdgcn_readfirstlane(qhi_g[b]);

    const int xi = x[b * LL + t];             // leaf index for this lane

    // ---- per-lane weights: rows 4qr..4qr+3 of W_rule[k]; row 15 zeroed ----
    float w[4][DD];
    #pragma unroll
    for (int ri = 0; ri < 4; ++ri) {
        int i = 4 * qr + ri;
        bool valid = (i < DD);
        const float* src = W_rule + k * DD * DD + (valid ? i * DD : 0);
        #pragma unroll
        for (int j = 0; j < DD; ++j) w[ri][j] = valid ? src[j] : 0.0f;
    }
    #pragma unroll
    for (int ri = 0; ri < 4; ++ri)
        #pragma unroll
        for (int j = 0; j < DD; ++j)
            asm("" : "+v"(w[ri][j]));          // materialize once in VGPRs

    // ---- W_lin row for the epilogue ----
    float wl[DD];
    {
        const float* wlp = W_lin + ((t < NCC) ? t : 0) * DD;
        #pragma unroll
        for (int d = 0; d < DD; ++d) wl[d] = wlp[d];
    }

    // ---- normalize emb rows into LDS once per block; pad col15 = 0 ----
    if (tb < NCC + 1) {
        float v[DD]; float ssum = 0.f;
        #pragma unroll
        for (int d = 0; d < DD; ++d) { v[d] = emb[tb * DD + d]; ssum += v[d] * v[d]; }
        float inv = __builtin_amdgcn_rsqf(ssum * (1.0f / DD) + 1e-6f);
        #pragma unroll
        for (int d = 0; d < DD; ++d) nemb[tb][d] = v[d] * inv;
        nemb[tb][DD] = 0.0f;
    }
    __syncthreads();                           // the only barrier

    // ---- materialize leaves: tree row 63+t = nemb[xi] (col15 pad copies as 0) ----
    #pragma unroll
    for (int j = 0; j < 4; ++j)
        ((float4*)&tw[63 + t][0])[j] = ((const float4*)&nemb[xi][0])[j];

    // ---- single rolled loop over levels 5..0: build (lvl>0) + query boundary ----
    #pragma clang loop unroll(disable)
    for (int lvl = 5; lvl >= 0; --lvl) {
        const int n = 1 << lvl, first = n - 1;
        const int sh = 6 - lvl, shc = sh - 1;

        if (lvl > 0) {
            const int nst = (n > 8) ? (n >> 3) : 1;
            #pragma clang loop unroll(disable)
            for (int st = 0; st < nst; ++st) {
                int pi = (n >= 8) ? (st * 8 + g) : (g & (n - 1));
                int p = first + pi;
                float o0, o1;
                combine_ptr(&tw[2 * p + 1][0], &tw[2 * p + 2][0], w, k, qr, u, o0, o1);
                if (n >= 8 || g < n)
                    ((float2*)&tw[p][0])[u] = make_float2(o0, o1);
            }
        }
        {
            int bnd = g2 ? qh : ql;
            int piq = bnd >> sh;
            int p = first + piq;
            int lo = piq << sh, hi = lo + (1 << sh) - 1;
            bool full = (ql <= lo) && (qh >= hi);
            int lo1 = (2 * piq) << shc,     hi1 = lo1 + (1 << shc) - 1;
            int lo2 = (2 * piq + 1) << shc, hi2 = lo2 + (1 << shc) - 1;
            bool d1 = (ql > hi1) || (qh < lo1);
            bool d2 = (ql > hi2) || (qh < lo2);
            const float* Lp = d1 ? &nemb[NCC][0] : &tw[2 * p + 1][0];
            const float* Rp = d2 ? &nemb[NCC][0] : &tw[2 * p + 2][0];
            float o0, o1;
            combine_ptr(Lp, Rp, w, k, qr, u, o0, o1);
            bool we = (t < 16) && (lvl == 0 ? (g2 == 0)
                                            : (!full && (g2 == 0 || piq != (ql >> sh))));
            if (we) ((float2*)&tw[p][0])[u] = make_float2(o0, o1);
        }
    }

    // ---- output: out[b] = Q(root) @ W_lin.T ----
    if (active && t < NCC) {
        float acc = 0.f;
        #pragma unroll
        for (int d = 0; d < DD; ++d) acc = fmaf(tw[0][d], wl[d], acc);
        out[b * NCC + t] = acc;
    }
}

extern "C" void kernel_launch(void* const* d_in, const int* in_sizes, int n_in,
                              void* d_out, int out_size, void* d_ws, size_t ws_size,
                              hipStream_t stream) {
    const float* emb    = (const float*)d_in[0];
    const float* W_lin  = (const float*)d_in[1];
    const float* W_rule = (const float*)d_in[2];
    const int*   x      = (const int*)d_in[3];
    const int*   qlo    = (const int*)d_in[4];
    const int*   qhi    = (const int*)d_in[5];
    float* outp = (float*)d_out;

    int bsz = in_sizes[3] / LL;               // 2048
    int nblk = (bsz + EPB - 1) / EPB;         // 512
    seg_tree_kernel<<<dim3(nblk), dim3(256), 0, stream>>>(
        emb, W_lin, W_rule, x, qlo, qhi, outp, bsz);
}